// Round 1
// 662.574 us; speedup vs baseline: 1.2266x; 1.2266x over previous
//
#include <hip/hip_runtime.h>
#include <hip/hip_bf16.h>

// Gramba (fp32 in / fp32 out): x_in = silu(x@W1+b1); x_skip = silu(x@W2+b2)
//         z = sigmoid(x_in@Wz+bz); h~ = x_in@Wh+bh
//         h = scan(h = (1-z)h + z*h~); out = (x_skip+h)@Wo + bo
// R9: (a) scan -> 256 blocks (32-col x 32-seg), register-cached (a,b) so the
//     second pass never re-reads rawzh; XCD-paired block remap keeps the two
//     64B halves of each 128B line on one XCD L2.
//     (b) GEMM epilogue LDS cut 36->32 KB (2-pass [64][136] bf16 tile) ->
//     5 blocks/CU; stride 136 breaks the 8-way quad-row write conflicts.
//     (c) MODE 3 epilogue: 4-pass [32][132] fp32 LDS stage -> coalesced
//     dwordx4 stores instead of 64 scattered 4B column stores.
// K-loop unchanged: double-buffered vmcnt(4) pipeline, XOR-swizzled LDS.
//
// Workspace layout (183 MiB):
//   [0,32)    rawzh chunk (bf16, 4096x4096)   [xb overlays [0,16) before use]
//   [32,33)   carry (fp32 h state, 4x2048)
//   [33,97)   xin   (bf16, 16384x2048)
//   [97,161)  xskip (bf16; scan overwrites with s = x_skip+h)
//   [161,165) Wt12  (bf16 [4096][512])
//   [165,181) Wtzh  (bf16 [4096][2048])
//   [181,183) Wto   (bf16 [512][2048])

typedef __bf16 bf16x8 __attribute__((ext_vector_type(8)));
typedef __bf16 bf16x4 __attribute__((ext_vector_type(4)));
typedef float  f32x4  __attribute__((ext_vector_type(4)));

#define DEVINL __device__ __forceinline__

DEVINL void async_ld16(const __bf16* g, __bf16* l) {
    __builtin_amdgcn_global_load_lds(
        (const __attribute__((address_space(1))) void*)g,
        (__attribute__((address_space(3))) void*)l, 16, 0, 0);
}

DEVINL float fsigmoid(float v) { return 1.0f / (1.0f + __expf(-v)); }

struct KLoopSM { __bf16 A[2][128 * 32]; __bf16 B[2][128 * 32]; };  // 32 KB

// MODE 0: dual split-silu -> bf16 out/out2 | MODE 3: fp32 out (staged)
// MODE 4: bf16 out, dual bias split at 2048
template <int MODE>
__global__ __launch_bounds__(256)
void gemm_bt(const __bf16* __restrict__ A, const __bf16* __restrict__ Bt,
             const float* __restrict__ bias, const float* __restrict__ bias2,
             void* __restrict__ out, void* __restrict__ out2, int N, int K,
             int bps, int seg_stride, int row_off)
{
    __shared__ union SM {
        KLoopSM kl;                 // 32768 B
        __bf16 ct[64 * 136];        // 17408 B: 2-pass bf16 epilogue tile
        float  ctf[32 * 132];       // 16896 B: 4-pass fp32 epilogue tile
    } sm;
    const int tid = threadIdx.x;
    const int bx = blockIdx.x;
    const int seg = bx / bps;
    const int within = bx - seg * bps;
    const int gm0 = row_off + seg * seg_stride + within * 128;  // A row base
    const int om0 = bx * 128;                                   // out row base
    const int n0 = blockIdx.y * 128;

    // Staging: 8KB tile = 512 x 16B chunks. Slot c holds global chunk
    // (row = c>>2, kc = (c&3) ^ ((c>>3)&3)) -- XOR swizzle, conflict-free.
    const int c0 = tid, c1 = tid + 256;
    const int r0 = c0 >> 2, k0 = (c0 & 3) ^ ((c0 >> 3) & 3);
    const int r1 = c1 >> 2, k1 = (c1 & 3) ^ ((c1 >> 3) & 3);
    const __bf16* Ag0 = A  + (size_t)(gm0 + r0) * K + k0 * 8;
    const __bf16* Ag1 = A  + (size_t)(gm0 + r1) * K + k1 * 8;
    const __bf16* Bg0 = Bt + (size_t)(n0 + r0) * K + k0 * 8;
    const __bf16* Bg1 = Bt + (size_t)(n0 + r1) * K + k1 * 8;

    const int lane = tid & 63;
    const int wave = tid >> 6;
    const int wrow = (wave >> 1) * 64;
    const int wcol = (wave & 1) * 64;
    const int quad = lane >> 4;
    const int r = lane & 15;
    const int swz = (quad ^ ((r >> 1) & 3)) * 8;

    f32x4 acc[4][4] = {};

    const int T = K >> 5;
    async_ld16(Ag0, sm.kl.A[0] + c0 * 8);
    async_ld16(Ag1, sm.kl.A[0] + c1 * 8);
    async_ld16(Bg0, sm.kl.B[0] + c0 * 8);
    async_ld16(Bg1, sm.kl.B[0] + c1 * 8);

    for (int t = 0; t < T; ++t) {
        const int cur = t & 1;
        if (t + 1 < T) {
            const int kt = (t + 1) << 5;
            async_ld16(Ag0 + kt, sm.kl.A[cur ^ 1] + c0 * 8);
            async_ld16(Ag1 + kt, sm.kl.A[cur ^ 1] + c1 * 8);
            async_ld16(Bg0 + kt, sm.kl.B[cur ^ 1] + c0 * 8);
            async_ld16(Bg1 + kt, sm.kl.B[cur ^ 1] + c1 * 8);
            asm volatile("s_waitcnt vmcnt(4)\n\ts_barrier" ::: "memory");
        } else {
            asm volatile("s_waitcnt vmcnt(0)\n\ts_barrier" ::: "memory");
        }

        const __bf16* ap = sm.kl.A[cur] + (wrow + r) * 32 + swz;
        const __bf16* bp = sm.kl.B[cur] + (wcol + r) * 32 + swz;
        bf16x8 af[4], bf_[4];
#pragma unroll
        for (int i = 0; i < 4; ++i) af[i] = *(const bf16x8*)(ap + i * 512);
#pragma unroll
        for (int i = 0; i < 4; ++i) bf_[i] = *(const bf16x8*)(bp + i * 512);
#pragma unroll
        for (int i = 0; i < 4; ++i)
#pragma unroll
            for (int j = 0; j < 4; ++j)
                acc[i][j] = __builtin_amdgcn_mfma_f32_16x16x32_bf16(
                    af[i], bf_[j], acc[i][j], 0, 0, 0);

        asm volatile("s_waitcnt lgkmcnt(0)\n\ts_barrier" ::: "memory");
    }

    // C/D layout (m89): col = lane&15, row = (lane>>4)*4 + reg
    if (MODE == 3) {
        // fp32 staged epilogue: 4 passes of 32 rows through [32][132] LDS,
        // then coalesced dwordx4 stores (was: 64 scattered 4B column stores).
        float bvj[4];
#pragma unroll
        for (int j = 0; j < 4; ++j)
            bvj[j] = bias[n0 + wcol + j * 16 + r];
#pragma unroll
        for (int p = 0; p < 4; ++p) {
#pragma unroll
            for (int j = 0; j < 4; ++j)
#pragma unroll
                for (int k = 0; k < 4; ++k)
                    sm.ctf[((wave >> 1) * 16 + quad * 4 + k) * 132 +
                           (wcol + j * 16 + r)] = acc[p][j][k] + bvj[j];
            __syncthreads();
#pragma unroll
            for (int q = 0; q < 4; ++q) {
                const int chunk = q * 256 + tid;      // 0..1023
                const int trow = chunk >> 5;          // 0..31
                const int tc4 = (chunk & 31) * 4;     // fp32 col, x4 chunk
                const f32x4 vv = *(const f32x4*)(sm.ctf + trow * 132 + tc4);
                const int grow = om0 + (trow >> 4) * 64 + p * 16 + (trow & 15);
                *(f32x4*)((float*)out + (size_t)grow * N + n0 + tc4) = vv;
            }
            __syncthreads();
        }
    } else {
        // bf16: 2 passes of 64 rows through [64][136] LDS (stride 136 keeps
        // quad-rows on distinct banks), then coalesced 16B stores.
        const bool lo = n0 < 2048;   // tile-uniform (n0 multiple of 128)
        __bf16* dst;
        int cb;
        size_t stride;
        if (MODE == 0) {
            dst = lo ? (__bf16*)out : (__bf16*)out2;
            cb = lo ? n0 : n0 - 2048;
            stride = 2048;
        } else {
            dst = (__bf16*)out;
            cb = n0;
            stride = (size_t)N;
        }
        float bvj[4];
#pragma unroll
        for (int j = 0; j < 4; ++j) {
            const int gc = n0 + wcol + j * 16 + r;
            bvj[j] = lo ? bias[gc] : bias2[gc - 2048];
        }
#pragma unroll
        for (int p = 0; p < 2; ++p) {
#pragma unroll
            for (int ii = 0; ii < 2; ++ii) {
                const int i = 2 * p + ii;
#pragma unroll
                for (int j = 0; j < 4; ++j)
#pragma unroll
                    for (int k = 0; k < 4; ++k) {
                        const float v = acc[i][j][k] + bvj[j];
                        const __bf16 o = (MODE == 0) ? (__bf16)(v * fsigmoid(v))
                                                     : (__bf16)v;
                        sm.ct[((wave >> 1) * 32 + ii * 16 + quad * 4 + k) * 136 +
                              (wcol + j * 16 + r)] = o;
                    }
            }
            __syncthreads();
#pragma unroll
            for (int q = 0; q < 4; ++q) {
                const int chunk = q * 256 + tid;      // 0..1023
                const int trow = chunk >> 4;          // 0..63
                const int tc = (chunk & 15) * 8;      // bf16 col, x8 chunk
                const bf16x8 vv = *(const bf16x8*)(sm.ct + trow * 136 + tc);
                const int grow = om0 + (trow >> 5) * 64 + p * 32 + (trow & 31);
                *(bf16x8*)(dst + (size_t)grow * stride + cb + tc) = vv;
            }
            __syncthreads();
        }
    }
}

// Parallel minGRU scan over one chunk, on raw pre-activations:
// z = sigmoid(raw_z), b = z * raw_h, h = (1-z)h + b.
// raw is [B*CS][4096] (z cols 0..2047, h cols 2048..4095).
// R9: 256 blocks (full chip), 32-col groups x 32 segments x 1024 threads.
// (a,b) per timestep cached in registers (L=32 -> 64 VGPR) so the apply
// pass never re-reads raw. Block remap pairs adjacent col-groups per XCD
// so both 64B halves of each 128B raw/xskip line stay in one L2.
#define SSEG 32
#define SCOLS 32
__global__ __launch_bounds__(1024)
void scan_kernel(const __bf16* __restrict__ raw, __bf16* __restrict__ xskip,
                 float* __restrict__ carry, int CS, int S, int t0, int first)
{
    __shared__ float Als[SSEG][SCOLS];
    __shared__ float Bls[SSEG][SCOLS];
    const int lane = threadIdx.x & (SCOLS - 1);   // col within group
    const int w = threadIdx.x >> 5;               // segment 0..31
    // XCD-pairing remap: round-robin %8 dispatch -> give each XCD a
    // contiguous range of linear ids (256 blocks, 256%8==0 -> bijective).
    const int nb8 = gridDim.x >> 3;
    const int lin = (blockIdx.x & 7) * nb8 + (blockIdx.x >> 3);
    const int gpb = 2048 / SCOLS;                 // 64 groups per batch
    const int batch = lin / gpb;
    const int col = (lin - batch * gpb) * SCOLS + lane;
    const int L = CS / SSEG;                      // 32 (CS always 1024)
    const int tbeg = w * L;

    const size_t rbase = ((size_t)batch * CS + tbeg) * 4096 + col;

    float av[32], bv[32];
    float A = 1.0f, Bv = 0.0f;
    {
        size_t idx = rbase;
#pragma unroll
        for (int t = 0; t < 32; ++t, idx += 4096) {
            const float z = fsigmoid((float)raw[idx]);
            const float b = z * (float)raw[idx + 2048];
            const float a = 1.0f - z;
            av[t] = a;
            bv[t] = b;
            Bv = a * Bv + b;
            A *= a;
        }
    }
    Als[w][lane] = A;
    Bls[w][lane] = Bv;
    __syncthreads();

    const int ch = batch * 2048 + col;
    float h = first ? 0.0f : carry[ch];
    for (int s = 0; s < w; ++s)
        h = Als[s][lane] * h + Bls[s][lane];
    if (w == SSEG - 1)
        carry[ch] = A * h + Bv;

    {
        size_t gidx = ((size_t)batch * S + t0 + tbeg) * 2048 + col;
#pragma unroll
        for (int t = 0; t < 32; ++t, gidx += 2048) {
            h = av[t] * h + bv[t];
            xskip[gidx] = (__bf16)((float)xskip[gidx] + h);
        }
    }
}

__global__ __launch_bounds__(256)
void conv_f32_bf16(const float* __restrict__ x, __bf16* __restrict__ y, int n4)
{
    const int i = blockIdx.x * 256 + threadIdx.x;
    if (i >= n4) return;
    const float4 v = ((const float4*)x)[i];
    bf16x4 o;
    o[0] = (__bf16)v.x; o[1] = (__bf16)v.y; o[2] = (__bf16)v.z; o[3] = (__bf16)v.w;
    ((bf16x4*)y)[i] = o;
}

// W[K][N] fp32 -> Wt[N][K] bf16
__global__ __launch_bounds__(256)
void transpose_bf16(const float* __restrict__ W, __bf16* __restrict__ Wt, int K, int N)
{
    __shared__ float tile[32][33];
    const int tx = threadIdx.x & 31;
    const int ty = threadIdx.x >> 5;
    const int nb = blockIdx.x * 32;
    const int kb = blockIdx.y * 32;
#pragma unroll
    for (int i = 0; i < 32; i += 8)
        tile[ty + i][tx] = W[(size_t)(kb + ty + i) * N + nb + tx];
    __syncthreads();
#pragma unroll
    for (int i = 0; i < 32; i += 8)
        Wt[(size_t)(nb + ty + i) * K + kb + tx] = (__bf16)tile[tx][ty + i];
}

extern "C" void kernel_launch(void* const* d_in, const int* in_sizes, int n_in,
                              void* d_out, int out_size, void* d_ws, size_t ws_size,
                              hipStream_t stream)
{
    const float* x     = (const float*)d_in[0];
    const float* W_in1 = (const float*)d_in[1];
    const float* b_in1 = (const float*)d_in[2];
    const float* W_in2 = (const float*)d_in[3];
    const float* b_in2 = (const float*)d_in[4];
    const float* W_z   = (const float*)d_in[5];
    const float* b_z   = (const float*)d_in[6];
    const float* W_h   = (const float*)d_in[7];
    const float* b_h   = (const float*)d_in[8];
    const float* W_out = (const float*)d_in[9];
    const float* b_out = (const float*)d_in[10];

    const int B = 4, S = 4096, H = 512, E = 2048;
    const int M = B * S;        // 16384
    const int CS = 1024;        // chunk length
    const int NC = S / CS;      // 4 chunks
    const int MC = B * CS;      // 4096 rows per chunk

    const size_t MiB = 1024 * 1024;
    const size_t NEEDED = 183 * MiB;
    if (ws_size < NEEDED) return;

    char* ws = (char*)d_ws;
    __bf16* xb    = (__bf16*)(ws + 0);        // overlaid by rawzh after use
    __bf16* rawzh = (__bf16*)(ws + 0);
    float*  carry = (float*) (ws + 32 * MiB);
    __bf16* xin   = (__bf16*)(ws + 33 * MiB);
    __bf16* xskip = (__bf16*)(ws + 97 * MiB);
    __bf16* Wt12  = (__bf16*)(ws + 161 * MiB);
    __bf16* Wtzh  = (__bf16*)(ws + 165 * MiB);
    __bf16* Wto   = (__bf16*)(ws + 181 * MiB);

    conv_f32_bf16<<<(M * H / 4 + 255) / 256, 256, 0, stream>>>(x, xb, M * H / 4);
    transpose_bf16<<<dim3(E / 32, H / 32), 256, 0, stream>>>(W_in1, Wt12, H, E);
    transpose_bf16<<<dim3(E / 32, H / 32), 256, 0, stream>>>(W_in2, Wt12 + (size_t)E * H, H, E);
    transpose_bf16<<<dim3(E / 32, E / 32), 256, 0, stream>>>(W_z, Wtzh, E, E);
    transpose_bf16<<<dim3(E / 32, E / 32), 256, 0, stream>>>(W_h, Wtzh + (size_t)E * E, E, E);
    transpose_bf16<<<dim3(H / 32, E / 32), 256, 0, stream>>>(W_out, Wto, E, H);

    // Merged input GEMM: N=4096 (W1|W2), split-silu epilogue -> xin / xskip
    gemm_bt<0><<<dim3(M / 128, 2 * E / 128), 256, 0, stream>>>(
        xb, Wt12, b_in1, b_in2, xin, xskip, 2 * E, H, M / 128, 0, 0);

    // Recurrent stage, chunked over S (rawzh overlays dead xb)
    for (int c = 0; c < NC; ++c) {
        const int row_off = c * CS;
        gemm_bt<4><<<dim3(MC / 128, 2 * E / 128), 256, 0, stream>>>(
            xin, Wtzh, b_z, b_h, rawzh, nullptr, 2 * E, E, CS / 128, S, row_off);
        scan_kernel<<<(B * E) / SCOLS, 1024, 0, stream>>>(
            rawzh, xskip, carry, CS, S, row_off, c == 0);
    }

    // Output GEMM (full M), fp32 out
    gemm_bt<3><<<dim3(M / 128, H / 128), 256, 0, stream>>>(
        xskip, Wto, b_out, nullptr, (float*)d_out, nullptr, H, E, M / 128, 0, 0);
}

// Round 3
// 607.212 us; speedup vs baseline: 1.3384x; 1.0912x over previous
//
#include <hip/hip_runtime.h>
#include <hip/hip_bf16.h>

// Gramba (fp32 in / fp32 out): x_in = silu(x@W1+b1); x_skip = silu(x@W2+b2)
//         z = sigmoid(x_in@Wz+bz); h~ = x_in@Wh+bh
//         h = scan(h = (1-z)h + z*h~); out = (x_skip+h)@Wo + bo
// R11: R10's 256x256 gemm3 with the epilogue LDS tile stride fixed:
//   ct was [64*136] (copied from the 128-wide kernel) but the 256^2 tile
//   writes 256 columns -> rows aliased -> absmax 4.17. Now [64*264]
//   (stride 264 = 256+8: 16B-aligned rows, 4-way write / conflict-free read).
// gemm3: BK=32, 512 thr (8 waves, 2Mx4N, 128x64/wave), QUAD-buffered LDS,
//   staging 3 K-tiles ahead, counted vmcnt(8) (never 0 in steady state), ONE
//   barrier per K-tile, 32 MFMA between barriers, setprio around MFMA.
// Output GEMM keeps the 128^2 kernel (N=512). Scan: R9 version, unchanged.
//
// Workspace layout (183 MiB):
//   [0,32)    rawzh chunk (bf16, 4096x4096)   [xb overlays [0,16) before use]
//   [32,33)   carry (fp32 h state, 4x2048)
//   [33,97)   xin   (bf16, 16384x2048)
//   [97,161)  xskip (bf16; scan overwrites with s = x_skip+h)
//   [161,165) Wt12  (bf16 [4096][512])
//   [165,181) Wtzh  (bf16 [4096][2048])
//   [181,183) Wto   (bf16 [512][2048])

typedef __bf16 bf16x8 __attribute__((ext_vector_type(8)));
typedef __bf16 bf16x4 __attribute__((ext_vector_type(4)));
typedef float  f32x4  __attribute__((ext_vector_type(4)));

#define DEVINL __device__ __forceinline__

DEVINL void async_ld16(const __bf16* g, __bf16* l) {
    __builtin_amdgcn_global_load_lds(
        (const __attribute__((address_space(1))) void*)g,
        (__attribute__((address_space(3))) void*)l, 16, 0, 0);
}

DEVINL float fsigmoid(float v) { return 1.0f / (1.0f + __expf(-v)); }

// ---------------------------------------------------------------------------
// gemm3: 256x256 tile, BK=32, 512 threads, quad-buffered counted-vmcnt loop.
// MODE 0: dual split-silu -> bf16 out/out2 (split at col 2048)
// MODE 4: bf16 out, dual bias split at 2048
// Requires K >= 128 (T >= 4). A is [M][K] bf16, Bt is [N][K] bf16.
// ---------------------------------------------------------------------------
template <int MODE>
__global__ __launch_bounds__(512, 2)
void gemm3(const __bf16* __restrict__ A, const __bf16* __restrict__ Bt,
           const float* __restrict__ bias, const float* __restrict__ bias2,
           void* __restrict__ out, void* __restrict__ out2, int N, int K,
           int bps, int seg_stride, int row_off)
{
    __shared__ union SM3 {
        __bf16 kl[4][2][256 * 32];   // [buf][A=0/B=1][256 rows x 32 k] 128 KiB
        __bf16 ct[64 * 264];         // 33 KiB epilogue tile (64 x 256, pad 8)
    } sm;
    const int tid = threadIdx.x;                 // 0..511
    const int bx = blockIdx.x;
    const int seg = bx / bps;
    const int within = bx - seg * bps;
    const int gm0 = row_off + seg * seg_stride + within * 256;  // A row base
    const int om0 = bx * 256;                                   // out row base
    const int n0 = blockIdx.y * 256;

    // Staging: 16KB tile = 1024 x 16B chunks. Slot c holds global chunk
    // (row = c>>2, kc = (c&3) ^ ((c>>3)&3)) -- per-lane global swizzle,
    // linear LDS dest (global_load_lds requirement), conflict-free reads.
    const int c0 = tid, c1 = tid + 512;
    const int r0 = c0 >> 2, k0 = (c0 & 3) ^ ((c0 >> 3) & 3);
    const int r1 = c1 >> 2, k1 = (c1 & 3) ^ ((c1 >> 3) & 3);
    const __bf16* Ag0 = A  + (size_t)(gm0 + r0) * K + k0 * 8;
    const __bf16* Ag1 = A  + (size_t)(gm0 + r1) * K + k1 * 8;
    const __bf16* Bg0 = Bt + (size_t)(n0 + r0) * K + k0 * 8;
    const __bf16* Bg1 = Bt + (size_t)(n0 + r1) * K + k1 * 8;

    const int lane = tid & 63;
    const int wave = tid >> 6;
    const int wm = wave >> 2;        // 0..1  (M half: 128 rows)
    const int wn = wave & 3;         // 0..3  (N quarter: 64 cols)
    const int quad = lane >> 4;
    const int r = lane & 15;
    const int swz = (quad ^ ((r >> 1) & 3)) * 8;

    f32x4 acc[8][4] = {};

    const int T = K >> 5;            // K-tiles of 32

    auto stage = [&](int t, int b) {
        const int kt = t << 5;
        async_ld16(Ag0 + kt, sm.kl[b][0] + c0 * 8);
        async_ld16(Ag1 + kt, sm.kl[b][0] + c1 * 8);
        async_ld16(Bg0 + kt, sm.kl[b][1] + c0 * 8);
        async_ld16(Bg1 + kt, sm.kl[b][1] + c1 * 8);
    };

    // Prologue: stage 3 tiles ahead (12 loads outstanding).
    stage(0, 0);
    stage(1, 1);
    stage(2, 2);

    for (int t = 0; t < T; ++t) {
        // vmcnt ensures tile t's 4 loads (issued 3 iters ago) have LANDED;
        // barrier publishes all waves' loads + retires prev-iter ds_reads.
        // Outstanding at this point: tiles t+1, t+2 (8 loads) steady state.
        if (t + 2 < T) {
            asm volatile("s_waitcnt vmcnt(8)\n\ts_barrier" ::: "memory");
        } else if (t + 1 < T) {
            asm volatile("s_waitcnt vmcnt(4)\n\ts_barrier" ::: "memory");
        } else {
            asm volatile("s_waitcnt vmcnt(0)\n\ts_barrier" ::: "memory");
        }
        // Stage tile t+3 into buf (t+3)&3 == (t-1)&3: safe, every wave is
        // past its iter t-1 reads of that buffer (lgkmcnt before its MFMAs).
        if (t + 3 < T) stage(t + 3, (t + 3) & 3);

        const __bf16* ap = sm.kl[t & 3][0] + (wm * 128 + r) * 32 + swz;
        const __bf16* bp = sm.kl[t & 3][1] + (wn * 64 + r) * 32 + swz;
        bf16x8 af[8], bf_[4];
#pragma unroll
        for (int m = 0; m < 8; ++m) af[m] = *(const bf16x8*)(ap + m * 512);
#pragma unroll
        for (int n = 0; n < 4; ++n) bf_[n] = *(const bf16x8*)(bp + n * 512);

        __builtin_amdgcn_s_setprio(1);
#pragma unroll
        for (int m = 0; m < 8; ++m)
#pragma unroll
            for (int n = 0; n < 4; ++n)
                acc[m][n] = __builtin_amdgcn_mfma_f32_16x16x32_bf16(
                    af[m], bf_[n], acc[m][n], 0, 0, 0);
        __builtin_amdgcn_s_setprio(0);
    }

    // Epilogue. C/D layout (m89): col = lane&15, row = (lane>>4)*4 + reg.
    // Wave (wm,wn) owns rows om0+wm*128+m*16, cols n0+wn*64+nf*16.
    __syncthreads();   // all waves out of the K-loop before union reuse

    const bool lo = n0 < 2048;       // tile-uniform (n0 multiple of 256)
    __bf16* dst;
    int cb;
    size_t stride;
    if (MODE == 0) {
        dst = lo ? (__bf16*)out : (__bf16*)out2;
        cb = lo ? n0 : n0 - 2048;
        stride = 2048;
    } else {
        dst = (__bf16*)out;
        cb = n0;
        stride = (size_t)N;
    }
    float bvj[4];
#pragma unroll
    for (int nf = 0; nf < 4; ++nf) {
        const int gc = n0 + wn * 64 + nf * 16 + r;
        bvj[nf] = lo ? bias[gc] : bias2[gc - 2048];
    }

#pragma unroll
    for (int p = 0; p < 4; ++p) {
        // Pass p covers global rows om0 + p*64 .. +63 -> waves with wm==p>>1,
        // M-fragments (p&1)*4 .. +3. LDS tile: 64 rows x 256 cols, stride 264.
        if (wm == (p >> 1)) {
            const int mb = (p & 1) * 4;
#pragma unroll
            for (int mm = 0; mm < 4; ++mm)
#pragma unroll
                for (int nf = 0; nf < 4; ++nf)
#pragma unroll
                    for (int k = 0; k < 4; ++k) {
                        const float v = acc[mb + mm][nf][k] + bvj[nf];
                        const __bf16 o = (MODE == 0) ? (__bf16)(v * fsigmoid(v))
                                                     : (__bf16)v;
                        sm.ct[(mm * 16 + quad * 4 + k) * 264 +
                              (wn * 64 + nf * 16 + r)] = o;
                    }
        }
        __syncthreads();
#pragma unroll
        for (int q = 0; q < 4; ++q) {
            const int chunk = q * 512 + tid;      // 0..2047
            const int trow = chunk >> 5;          // 0..63
            const int tc = (chunk & 31) * 8;      // bf16 col, x8 chunk
            const bf16x8 vv = *(const bf16x8*)(sm.ct + trow * 264 + tc);
            *(bf16x8*)(dst + (size_t)(om0 + p * 64 + trow) * stride + cb + tc) = vv;
        }
        __syncthreads();
    }
}

// ---------------------------------------------------------------------------
// Legacy 128x128 kernel, kept for the output GEMM (MODE 3: fp32 out, N=512).
// ---------------------------------------------------------------------------
struct KLoopSM { __bf16 A[2][128 * 32]; __bf16 B[2][128 * 32]; };  // 32 KB

template <int MODE>
__global__ __launch_bounds__(256)
void gemm_bt(const __bf16* __restrict__ A, const __bf16* __restrict__ Bt,
             const float* __restrict__ bias, const float* __restrict__ bias2,
             void* __restrict__ out, void* __restrict__ out2, int N, int K,
             int bps, int seg_stride, int row_off)
{
    __shared__ union SM {
        KLoopSM kl;                 // 32768 B
        __bf16 ct[64 * 136];        // 17408 B: 2-pass bf16 epilogue tile
        float  ctf[32 * 132];       // 16896 B: 4-pass fp32 epilogue tile
    } sm;
    const int tid = threadIdx.x;
    const int bx = blockIdx.x;
    const int seg = bx / bps;
    const int within = bx - seg * bps;
    const int gm0 = row_off + seg * seg_stride + within * 128;  // A row base
    const int om0 = bx * 128;                                   // out row base
    const int n0 = blockIdx.y * 128;

    const int c0 = tid, c1 = tid + 256;
    const int r0 = c0 >> 2, k0 = (c0 & 3) ^ ((c0 >> 3) & 3);
    const int r1 = c1 >> 2, k1 = (c1 & 3) ^ ((c1 >> 3) & 3);
    const __bf16* Ag0 = A  + (size_t)(gm0 + r0) * K + k0 * 8;
    const __bf16* Ag1 = A  + (size_t)(gm0 + r1) * K + k1 * 8;
    const __bf16* Bg0 = Bt + (size_t)(n0 + r0) * K + k0 * 8;
    const __bf16* Bg1 = Bt + (size_t)(n0 + r1) * K + k1 * 8;

    const int lane = tid & 63;
    const int wave = tid >> 6;
    const int wrow = (wave >> 1) * 64;
    const int wcol = (wave & 1) * 64;
    const int quad = lane >> 4;
    const int r = lane & 15;
    const int swz = (quad ^ ((r >> 1) & 3)) * 8;

    f32x4 acc[4][4] = {};

    const int T = K >> 5;
    async_ld16(Ag0, sm.kl.A[0] + c0 * 8);
    async_ld16(Ag1, sm.kl.A[0] + c1 * 8);
    async_ld16(Bg0, sm.kl.B[0] + c0 * 8);
    async_ld16(Bg1, sm.kl.B[0] + c1 * 8);

    for (int t = 0; t < T; ++t) {
        const int cur = t & 1;
        if (t + 1 < T) {
            const int kt = (t + 1) << 5;
            async_ld16(Ag0 + kt, sm.kl.A[cur ^ 1] + c0 * 8);
            async_ld16(Ag1 + kt, sm.kl.A[cur ^ 1] + c1 * 8);
            async_ld16(Bg0 + kt, sm.kl.B[cur ^ 1] + c0 * 8);
            async_ld16(Bg1 + kt, sm.kl.B[cur ^ 1] + c1 * 8);
            asm volatile("s_waitcnt vmcnt(4)\n\ts_barrier" ::: "memory");
        } else {
            asm volatile("s_waitcnt vmcnt(0)\n\ts_barrier" ::: "memory");
        }

        const __bf16* ap = sm.kl.A[cur] + (wrow + r) * 32 + swz;
        const __bf16* bp = sm.kl.B[cur] + (wcol + r) * 32 + swz;
        bf16x8 af[4], bf_[4];
#pragma unroll
        for (int i = 0; i < 4; ++i) af[i] = *(const bf16x8*)(ap + i * 512);
#pragma unroll
        for (int i = 0; i < 4; ++i) bf_[i] = *(const bf16x8*)(bp + i * 512);
#pragma unroll
        for (int i = 0; i < 4; ++i)
#pragma unroll
            for (int j = 0; j < 4; ++j)
                acc[i][j] = __builtin_amdgcn_mfma_f32_16x16x32_bf16(
                    af[i], bf_[j], acc[i][j], 0, 0, 0);

        asm volatile("s_waitcnt lgkmcnt(0)\n\ts_barrier" ::: "memory");
    }

    // C/D layout (m89): col = lane&15, row = (lane>>4)*4 + reg
    if (MODE == 3) {
        float bvj[4];
#pragma unroll
        for (int j = 0; j < 4; ++j)
            bvj[j] = bias[n0 + wcol + j * 16 + r];
#pragma unroll
        for (int p = 0; p < 4; ++p) {
#pragma unroll
            for (int j = 0; j < 4; ++j)
#pragma unroll
                for (int k = 0; k < 4; ++k)
                    sm.ctf[((wave >> 1) * 16 + quad * 4 + k) * 132 +
                           (wcol + j * 16 + r)] = acc[p][j][k] + bvj[j];
            __syncthreads();
#pragma unroll
            for (int q = 0; q < 4; ++q) {
                const int chunk = q * 256 + tid;      // 0..1023
                const int trow = chunk >> 5;          // 0..31
                const int tc4 = (chunk & 31) * 4;     // fp32 col, x4 chunk
                const f32x4 vv = *(const f32x4*)(sm.ctf + trow * 132 + tc4);
                const int grow = om0 + (trow >> 4) * 64 + p * 16 + (trow & 15);
                *(f32x4*)((float*)out + (size_t)grow * N + n0 + tc4) = vv;
            }
            __syncthreads();
        }
    } else {
        // (unused in this round's launches -- gemm3 handles MODE 0/4)
        const bool lo = n0 < 2048;
        __bf16* dst;
        int cb;
        size_t stride;
        if (MODE == 0) {
            dst = lo ? (__bf16*)out : (__bf16*)out2;
            cb = lo ? n0 : n0 - 2048;
            stride = 2048;
        } else {
            dst = (__bf16*)out;
            cb = n0;
            stride = (size_t)N;
        }
        float bvj[4];
#pragma unroll
        for (int j = 0; j < 4; ++j) {
            const int gc = n0 + wcol + j * 16 + r;
            bvj[j] = lo ? bias[gc] : bias2[gc - 2048];
        }
#pragma unroll
        for (int p = 0; p < 2; ++p) {
#pragma unroll
            for (int ii = 0; ii < 2; ++ii) {
                const int i = 2 * p + ii;
#pragma unroll
                for (int j = 0; j < 4; ++j)
#pragma unroll
                    for (int k = 0; k < 4; ++k) {
                        const float v = acc[i][j][k] + bvj[j];
                        const __bf16 o = (MODE == 0) ? (__bf16)(v * fsigmoid(v))
                                                     : (__bf16)v;
                        sm.ct[((wave >> 1) * 32 + ii * 16 + quad * 4 + k) * 136 +
                              (wcol + j * 16 + r)] = o;
                    }
            }
            __syncthreads();
#pragma unroll
            for (int q = 0; q < 4; ++q) {
                const int chunk = q * 256 + tid;
                const int trow = chunk >> 4;
                const int tc = (chunk & 15) * 8;
                const bf16x8 vv = *(const bf16x8*)(sm.ct + trow * 136 + tc);
                const int grow = om0 + (trow >> 5) * 64 + p * 32 + (trow & 31);
                *(bf16x8*)(dst + (size_t)grow * stride + cb + tc) = vv;
            }
            __syncthreads();
        }
    }
}

// Parallel minGRU scan over one chunk, on raw pre-activations:
// z = sigmoid(raw_z), b = z * raw_h, h = (1-z)h + b.
// raw is [B*CS][4096] (z cols 0..2047, h cols 2048..4095).
// 256 blocks (full chip), 32-col groups x 32 segments x 1024 threads.
// (a,b) per timestep cached in registers; XCD-paired block remap.
#define SSEG 32
#define SCOLS 32
__global__ __launch_bounds__(1024)
void scan_kernel(const __bf16* __restrict__ raw, __bf16* __restrict__ xskip,
                 float* __restrict__ carry, int CS, int S, int t0, int first)
{
    __shared__ float Als[SSEG][SCOLS];
    __shared__ float Bls[SSEG][SCOLS];
    const int lane = threadIdx.x & (SCOLS - 1);   // col within group
    const int w = threadIdx.x >> 5;               // segment 0..31
    const int nb8 = gridDim.x >> 3;
    const int lin = (blockIdx.x & 7) * nb8 + (blockIdx.x >> 3);
    const int gpb = 2048 / SCOLS;                 // 64 groups per batch
    const int batch = lin / gpb;
    const int col = (lin - batch * gpb) * SCOLS + lane;
    const int L = CS / SSEG;                      // 32 (CS always 1024)
    const int tbeg = w * L;

    const size_t rbase = ((size_t)batch * CS + tbeg) * 4096 + col;

    float av[32], bv[32];
    float A = 1.0f, Bv = 0.0f;
    {
        size_t idx = rbase;
#pragma unroll
        for (int t = 0; t < 32; ++t, idx += 4096) {
            const float z = fsigmoid((float)raw[idx]);
            const float b = z * (float)raw[idx + 2048];
            const float a = 1.0f - z;
            av[t] = a;
            bv[t] = b;
            Bv = a * Bv + b;
            A *= a;
        }
    }
    Als[w][lane] = A;
    Bls[w][lane] = Bv;
    __syncthreads();

    const int ch = batch * 2048 + col;
    float h = first ? 0.0f : carry[ch];
    for (int s = 0; s < w; ++s)
        h = Als[s][lane] * h + Bls[s][lane];
    if (w == SSEG - 1)
        carry[ch] = A * h + Bv;

    {
        size_t gidx = ((size_t)batch * S + t0 + tbeg) * 2048 + col;
#pragma unroll
        for (int t = 0; t < 32; ++t, gidx += 2048) {
            h = av[t] * h + bv[t];
            xskip[gidx] = (__bf16)((float)xskip[gidx] + h);
        }
    }
}

__global__ __launch_bounds__(256)
void conv_f32_bf16(const float* __restrict__ x, __bf16* __restrict__ y, int n4)
{
    const int i = blockIdx.x * 256 + threadIdx.x;
    if (i >= n4) return;
    const float4 v = ((const float4*)x)[i];
    bf16x4 o;
    o[0] = (__bf16)v.x; o[1] = (__bf16)v.y; o[2] = (__bf16)v.z; o[3] = (__bf16)v.w;
    ((bf16x4*)y)[i] = o;
}

// W[K][N] fp32 -> Wt[N][K] bf16
__global__ __launch_bounds__(256)
void transpose_bf16(const float* __restrict__ W, __bf16* __restrict__ Wt, int K, int N)
{
    __shared__ float tile[32][33];
    const int tx = threadIdx.x & 31;
    const int ty = threadIdx.x >> 5;
    const int nb = blockIdx.x * 32;
    const int kb = blockIdx.y * 32;
#pragma unroll
    for (int i = 0; i < 32; i += 8)
        tile[ty + i][tx] = W[(size_t)(kb + ty + i) * N + nb + tx];
    __syncthreads();
#pragma unroll
    for (int i = 0; i < 32; i += 8)
        Wt[(size_t)(nb + ty + i) * K + kb + tx] = (__bf16)tile[tx][ty + i];
}

extern "C" void kernel_launch(void* const* d_in, const int* in_sizes, int n_in,
                              void* d_out, int out_size, void* d_ws, size_t ws_size,
                              hipStream_t stream)
{
    const float* x     = (const float*)d_in[0];
    const float* W_in1 = (const float*)d_in[1];
    const float* b_in1 = (const float*)d_in[2];
    const float* W_in2 = (const float*)d_in[3];
    const float* b_in2 = (const float*)d_in[4];
    const float* W_z   = (const float*)d_in[5];
    const float* b_z   = (const float*)d_in[6];
    const float* W_h   = (const float*)d_in[7];
    const float* b_h   = (const float*)d_in[8];
    const float* W_out = (const float*)d_in[9];
    const float* b_out = (const float*)d_in[10];

    const int B = 4, S = 4096, H = 512, E = 2048;
    const int M = B * S;        // 16384
    const int CS = 1024;        // chunk length
    const int NC = S / CS;      // 4 chunks
    const int MC = B * CS;      // 4096 rows per chunk

    const size_t MiB = 1024 * 1024;
    const size_t NEEDED = 183 * MiB;
    if (ws_size < NEEDED) return;

    char* ws = (char*)d_ws;
    __bf16* xb    = (__bf16*)(ws + 0);        // overlaid by rawzh after use
    __bf16* rawzh = (__bf16*)(ws + 0);
    float*  carry = (float*) (ws + 32 * MiB);
    __bf16* xin   = (__bf16*)(ws + 33 * MiB);
    __bf16* xskip = (__bf16*)(ws + 97 * MiB);
    __bf16* Wt12  = (__bf16*)(ws + 161 * MiB);
    __bf16* Wtzh  = (__bf16*)(ws + 165 * MiB);
    __bf16* Wto   = (__bf16*)(ws + 181 * MiB);

    conv_f32_bf16<<<(M * H / 4 + 255) / 256, 256, 0, stream>>>(x, xb, M * H / 4);
    transpose_bf16<<<dim3(E / 32, H / 32), 256, 0, stream>>>(W_in1, Wt12, H, E);
    transpose_bf16<<<dim3(E / 32, H / 32), 256, 0, stream>>>(W_in2, Wt12 + (size_t)E * H, H, E);
    transpose_bf16<<<dim3(E / 32, E / 32), 256, 0, stream>>>(W_z, Wtzh, E, E);
    transpose_bf16<<<dim3(E / 32, E / 32), 256, 0, stream>>>(W_h, Wtzh + (size_t)E * E, E, E);
    transpose_bf16<<<dim3(H / 32, E / 32), 256, 0, stream>>>(W_out, Wto, E, H);

    // Merged input GEMM: N=4096 (W1|W2), split-silu epilogue -> xin / xskip
    // 256^2 tiles: grid 64 x 16, K=512 (T=16).
    gemm3<0><<<dim3(M / 256, 2 * E / 256), 512, 0, stream>>>(
        xb, Wt12, b_in1, b_in2, xin, xskip, 2 * E, H, M / 256, 0, 0);

    // Recurrent stage, chunked over S (rawzh overlays dead xb)
    // 256^2 tiles: grid 16 x 16 = 256 blocks (1/CU), K=2048 (T=64).
    for (int c = 0; c < NC; ++c) {
        const int row_off = c * CS;
        gemm3<4><<<dim3(MC / 256, 2 * E / 256), 512, 0, stream>>>(
            xin, Wtzh, b_z, b_h, rawzh, nullptr, 2 * E, E, CS / 256, S, row_off);
        scan_kernel<<<(B * E) / SCOLS, 1024, 0, stream>>>(
            rawzh, xskip, carry, CS, S, row_off, c == 0);
    }

    // Output GEMM (full M), fp32 out -- legacy 128^2 kernel (N=512).
    gemm_bt<3><<<dim3(M / 128, H / 128), 256, 0, stream>>>(
        xskip, Wto, b_out, nullptr, (float*)d_out, nullptr, H, E, M / 128, 0, 0);
}

// Round 4
// 598.071 us; speedup vs baseline: 1.3589x; 1.0153x over previous
//
#include <hip/hip_runtime.h>
#include <hip/hip_bf16.h>

// Gramba (fp32 in / fp32 out): x_in = silu(x@W1+b1); x_skip = silu(x@W2+b2)
//         z = sigmoid(x_in@Wz+bz); h~ = x_in@Wh+bh
//         h = scan(h = (1-z)h + z*h~); out = (x_skip+h)@Wo + bo
// R12: split the GEMM structure by shape, per R3 counters:
//   - input GEMM (K=512, write-heavy): BACK to 128^2 gemm_bt<0> (measured
//     108 vs gemm3's 185 -- K=512 can't feed the 256^2 pipeline) + XCD-
//     contiguous swizzle (each XCD gets 16 bx panels x all by -> B L2-
//     resident, A-panel reads back-to-back).
//   - recurrent GEMMs (K=2048): stay on 256^2 gemm3<4> (105 -> ~75 us win).
//   - output GEMM (N=512): 128^2 gemm_bt<3>. Scan: R9 version.
//
// Workspace layout (183 MiB):
//   [0,32)    rawzh chunk (bf16, 4096x4096)   [xb overlays [0,16) before use]
//   [32,33)   carry (fp32 h state, 4x2048)
//   [33,97)   xin   (bf16, 16384x2048)
//   [97,161)  xskip (bf16; scan overwrites with s = x_skip+h)
//   [161,165) Wt12  (bf16 [4096][512])
//   [165,181) Wtzh  (bf16 [4096][2048])
//   [181,183) Wto   (bf16 [512][2048])

typedef __bf16 bf16x8 __attribute__((ext_vector_type(8)));
typedef __bf16 bf16x4 __attribute__((ext_vector_type(4)));
typedef float  f32x4  __attribute__((ext_vector_type(4)));

#define DEVINL __device__ __forceinline__

DEVINL void async_ld16(const __bf16* g, __bf16* l) {
    __builtin_amdgcn_global_load_lds(
        (const __attribute__((address_space(1))) void*)g,
        (__attribute__((address_space(3))) void*)l, 16, 0, 0);
}

DEVINL float fsigmoid(float v) { return 1.0f / (1.0f + __expf(-v)); }

// ---------------------------------------------------------------------------
// gemm3: 256x256 tile, BK=32, 512 threads, quad-buffered counted-vmcnt loop.
// Used for the recurrent GEMMs (K=2048, grid 16x16 = 1 block/CU).
// MODE 0: dual split-silu -> bf16 out/out2 | MODE 4: bf16 out, dual bias
// ---------------------------------------------------------------------------
template <int MODE>
__global__ __launch_bounds__(512, 2)
void gemm3(const __bf16* __restrict__ A, const __bf16* __restrict__ Bt,
           const float* __restrict__ bias, const float* __restrict__ bias2,
           void* __restrict__ out, void* __restrict__ out2, int N, int K,
           int bps, int seg_stride, int row_off)
{
    __shared__ union SM3 {
        __bf16 kl[4][2][256 * 32];   // [buf][A=0/B=1][256 rows x 32 k] 128 KiB
        __bf16 ct[64 * 264];         // 33 KiB epilogue tile (64 x 256, pad 8)
    } sm;
    const int tid = threadIdx.x;                 // 0..511
    const int bx = blockIdx.x;
    const int seg = bx / bps;
    const int within = bx - seg * bps;
    const int gm0 = row_off + seg * seg_stride + within * 256;  // A row base
    const int om0 = bx * 256;                                   // out row base
    const int n0 = blockIdx.y * 256;

    // Staging: 16KB tile = 1024 x 16B chunks. Slot c holds global chunk
    // (row = c>>2, kc = (c&3) ^ ((c>>3)&3)) -- per-lane global swizzle,
    // linear LDS dest (global_load_lds requirement), conflict-free reads.
    const int c0 = tid, c1 = tid + 512;
    const int r0 = c0 >> 2, k0 = (c0 & 3) ^ ((c0 >> 3) & 3);
    const int r1 = c1 >> 2, k1 = (c1 & 3) ^ ((c1 >> 3) & 3);
    const __bf16* Ag0 = A  + (size_t)(gm0 + r0) * K + k0 * 8;
    const __bf16* Ag1 = A  + (size_t)(gm0 + r1) * K + k1 * 8;
    const __bf16* Bg0 = Bt + (size_t)(n0 + r0) * K + k0 * 8;
    const __bf16* Bg1 = Bt + (size_t)(n0 + r1) * K + k1 * 8;

    const int lane = tid & 63;
    const int wave = tid >> 6;
    const int wm = wave >> 2;        // 0..1  (M half: 128 rows)
    const int wn = wave & 3;         // 0..3  (N quarter: 64 cols)
    const int quad = lane >> 4;
    const int r = lane & 15;
    const int swz = (quad ^ ((r >> 1) & 3)) * 8;

    f32x4 acc[8][4] = {};

    const int T = K >> 5;            // K-tiles of 32

    auto stage = [&](int t, int b) {
        const int kt = t << 5;
        async_ld16(Ag0 + kt, sm.kl[b][0] + c0 * 8);
        async_ld16(Ag1 + kt, sm.kl[b][0] + c1 * 8);
        async_ld16(Bg0 + kt, sm.kl[b][1] + c0 * 8);
        async_ld16(Bg1 + kt, sm.kl[b][1] + c1 * 8);
    };

    // Prologue: stage 3 tiles ahead (12 loads outstanding).
    stage(0, 0);
    stage(1, 1);
    stage(2, 2);

    for (int t = 0; t < T; ++t) {
        // vmcnt ensures tile t's 4 loads (issued 3 iters ago) have LANDED;
        // barrier publishes all waves' loads + retires prev-iter ds_reads.
        if (t + 2 < T) {
            asm volatile("s_waitcnt vmcnt(8)\n\ts_barrier" ::: "memory");
        } else if (t + 1 < T) {
            asm volatile("s_waitcnt vmcnt(4)\n\ts_barrier" ::: "memory");
        } else {
            asm volatile("s_waitcnt vmcnt(0)\n\ts_barrier" ::: "memory");
        }
        // Stage tile t+3 into buf (t+3)&3 == (t-1)&3: safe, every wave is
        // past its iter t-1 reads of that buffer (lgkmcnt before its MFMAs).
        if (t + 3 < T) stage(t + 3, (t + 3) & 3);

        const __bf16* ap = sm.kl[t & 3][0] + (wm * 128 + r) * 32 + swz;
        const __bf16* bp = sm.kl[t & 3][1] + (wn * 64 + r) * 32 + swz;
        bf16x8 af[8], bf_[4];
#pragma unroll
        for (int m = 0; m < 8; ++m) af[m] = *(const bf16x8*)(ap + m * 512);
#pragma unroll
        for (int n = 0; n < 4; ++n) bf_[n] = *(const bf16x8*)(bp + n * 512);

        __builtin_amdgcn_s_setprio(1);
#pragma unroll
        for (int m = 0; m < 8; ++m)
#pragma unroll
            for (int n = 0; n < 4; ++n)
                acc[m][n] = __builtin_amdgcn_mfma_f32_16x16x32_bf16(
                    af[m], bf_[n], acc[m][n], 0, 0, 0);
        __builtin_amdgcn_s_setprio(0);
    }

    // Epilogue. C/D layout (m89): col = lane&15, row = (lane>>4)*4 + reg.
    __syncthreads();   // all waves out of the K-loop before union reuse

    const bool lo = n0 < 2048;       // tile-uniform (n0 multiple of 256)
    __bf16* dst;
    int cb;
    size_t stride;
    if (MODE == 0) {
        dst = lo ? (__bf16*)out : (__bf16*)out2;
        cb = lo ? n0 : n0 - 2048;
        stride = 2048;
    } else {
        dst = (__bf16*)out;
        cb = n0;
        stride = (size_t)N;
    }
    float bvj[4];
#pragma unroll
    for (int nf = 0; nf < 4; ++nf) {
        const int gc = n0 + wn * 64 + nf * 16 + r;
        bvj[nf] = lo ? bias[gc] : bias2[gc - 2048];
    }

#pragma unroll
    for (int p = 0; p < 4; ++p) {
        // Pass p covers global rows om0 + p*64 .. +63 -> waves with wm==p>>1,
        // M-fragments (p&1)*4 .. +3. LDS tile: 64 rows x 256 cols, stride 264.
        if (wm == (p >> 1)) {
            const int mb = (p & 1) * 4;
#pragma unroll
            for (int mm = 0; mm < 4; ++mm)
#pragma unroll
                for (int nf = 0; nf < 4; ++nf)
#pragma unroll
                    for (int k = 0; k < 4; ++k) {
                        const float v = acc[mb + mm][nf][k] + bvj[nf];
                        const __bf16 o = (MODE == 0) ? (__bf16)(v * fsigmoid(v))
                                                     : (__bf16)v;
                        sm.ct[(mm * 16 + quad * 4 + k) * 264 +
                              (wn * 64 + nf * 16 + r)] = o;
                    }
        }
        __syncthreads();
#pragma unroll
        for (int q = 0; q < 4; ++q) {
            const int chunk = q * 512 + tid;      // 0..2047
            const int trow = chunk >> 5;          // 0..63
            const int tc = (chunk & 31) * 8;      // bf16 col, x8 chunk
            const bf16x8 vv = *(const bf16x8*)(sm.ct + trow * 264 + tc);
            *(bf16x8*)(dst + (size_t)(om0 + p * 64 + trow) * stride + cb + tc) = vv;
        }
        __syncthreads();
    }
}

// ---------------------------------------------------------------------------
// 128x128 kernel: input GEMM (MODE 0, K=512) + output GEMM (MODE 3, N=512).
// MODE 0 adds an XCD-contiguous block swizzle: each XCD owns a contiguous
// 1/8 slice of bx panels crossed with ALL by -> B panel (4 MB) L2-resident
// per XCD, A panels read gridDim.y times back-to-back (L2 hits).
// ---------------------------------------------------------------------------
struct KLoopSM { __bf16 A[2][128 * 32]; __bf16 B[2][128 * 32]; };  // 32 KB

template <int MODE>
__global__ __launch_bounds__(256)
void gemm_bt(const __bf16* __restrict__ A, const __bf16* __restrict__ Bt,
             const float* __restrict__ bias, const float* __restrict__ bias2,
             void* __restrict__ out, void* __restrict__ out2, int N, int K,
             int bps, int seg_stride, int row_off)
{
    __shared__ union SM {
        KLoopSM kl;                 // 32768 B
        __bf16 ct[64 * 136];        // 17408 B: 2-pass bf16 epilogue tile
        float  ctf[32 * 132];       // 16896 B: 4-pass fp32 epilogue tile
    } sm;
    const int tid = threadIdx.x;
    int bx = blockIdx.x;
    int by = blockIdx.y;
    if (MODE == 0) {
        // XCD-contiguous remap (requires gridDim.x % 8 == 0; bijective).
        // dispatch linear id (x-fast); XCD = lin % 8 (round-robin).
        const int lin = by * gridDim.x + bx;
        const int xcd = lin & 7;
        const int pos = lin >> 3;
        bx = xcd * (gridDim.x >> 3) + pos / gridDim.y;
        by = pos % gridDim.y;
    }
    const int seg = bx / bps;
    const int within = bx - seg * bps;
    const int gm0 = row_off + seg * seg_stride + within * 128;  // A row base
    const int om0 = bx * 128;                                   // out row base
    const int n0 = by * 128;

    const int c0 = tid, c1 = tid + 256;
    const int r0 = c0 >> 2, k0 = (c0 & 3) ^ ((c0 >> 3) & 3);
    const int r1 = c1 >> 2, k1 = (c1 & 3) ^ ((c1 >> 3) & 3);
    const __bf16* Ag0 = A  + (size_t)(gm0 + r0) * K + k0 * 8;
    const __bf16* Ag1 = A  + (size_t)(gm0 + r1) * K + k1 * 8;
    const __bf16* Bg0 = Bt + (size_t)(n0 + r0) * K + k0 * 8;
    const __bf16* Bg1 = Bt + (size_t)(n0 + r1) * K + k1 * 8;

    const int lane = tid & 63;
    const int wave = tid >> 6;
    const int wrow = (wave >> 1) * 64;
    const int wcol = (wave & 1) * 64;
    const int quad = lane >> 4;
    const int r = lane & 15;
    const int swz = (quad ^ ((r >> 1) & 3)) * 8;

    f32x4 acc[4][4] = {};

    const int T = K >> 5;
    async_ld16(Ag0, sm.kl.A[0] + c0 * 8);
    async_ld16(Ag1, sm.kl.A[0] + c1 * 8);
    async_ld16(Bg0, sm.kl.B[0] + c0 * 8);
    async_ld16(Bg1, sm.kl.B[0] + c1 * 8);

    for (int t = 0; t < T; ++t) {
        const int cur = t & 1;
        if (t + 1 < T) {
            const int kt = (t + 1) << 5;
            async_ld16(Ag0 + kt, sm.kl.A[cur ^ 1] + c0 * 8);
            async_ld16(Ag1 + kt, sm.kl.A[cur ^ 1] + c1 * 8);
            async_ld16(Bg0 + kt, sm.kl.B[cur ^ 1] + c0 * 8);
            async_ld16(Bg1 + kt, sm.kl.B[cur ^ 1] + c1 * 8);
            asm volatile("s_waitcnt vmcnt(4)\n\ts_barrier" ::: "memory");
        } else {
            asm volatile("s_waitcnt vmcnt(0)\n\ts_barrier" ::: "memory");
        }

        const __bf16* ap = sm.kl.A[cur] + (wrow + r) * 32 + swz;
        const __bf16* bp = sm.kl.B[cur] + (wcol + r) * 32 + swz;
        bf16x8 af[4], bf_[4];
#pragma unroll
        for (int i = 0; i < 4; ++i) af[i] = *(const bf16x8*)(ap + i * 512);
#pragma unroll
        for (int i = 0; i < 4; ++i) bf_[i] = *(const bf16x8*)(bp + i * 512);
#pragma unroll
        for (int i = 0; i < 4; ++i)
#pragma unroll
            for (int j = 0; j < 4; ++j)
                acc[i][j] = __builtin_amdgcn_mfma_f32_16x16x32_bf16(
                    af[i], bf_[j], acc[i][j], 0, 0, 0);

        asm volatile("s_waitcnt lgkmcnt(0)\n\ts_barrier" ::: "memory");
    }

    // C/D layout (m89): col = lane&15, row = (lane>>4)*4 + reg
    if (MODE == 3) {
        float bvj[4];
#pragma unroll
        for (int j = 0; j < 4; ++j)
            bvj[j] = bias[n0 + wcol + j * 16 + r];
#pragma unroll
        for (int p = 0; p < 4; ++p) {
#pragma unroll
            for (int j = 0; j < 4; ++j)
#pragma unroll
                for (int k = 0; k < 4; ++k)
                    sm.ctf[((wave >> 1) * 16 + quad * 4 + k) * 132 +
                           (wcol + j * 16 + r)] = acc[p][j][k] + bvj[j];
            __syncthreads();
#pragma unroll
            for (int q = 0; q < 4; ++q) {
                const int chunk = q * 256 + tid;      // 0..1023
                const int trow = chunk >> 5;          // 0..31
                const int tc4 = (chunk & 31) * 4;     // fp32 col, x4 chunk
                const f32x4 vv = *(const f32x4*)(sm.ctf + trow * 132 + tc4);
                const int grow = om0 + (trow >> 4) * 64 + p * 16 + (trow & 15);
                *(f32x4*)((float*)out + (size_t)grow * N + n0 + tc4) = vv;
            }
            __syncthreads();
        }
    } else {
        // bf16: 2 passes of 64 rows through [64][136] LDS, coalesced stores.
        const bool lo = n0 < 2048;
        __bf16* dst;
        int cb;
        size_t stride;
        if (MODE == 0) {
            dst = lo ? (__bf16*)out : (__bf16*)out2;
            cb = lo ? n0 : n0 - 2048;
            stride = 2048;
        } else {
            dst = (__bf16*)out;
            cb = n0;
            stride = (size_t)N;
        }
        float bvj[4];
#pragma unroll
        for (int j = 0; j < 4; ++j) {
            const int gc = n0 + wcol + j * 16 + r;
            bvj[j] = lo ? bias[gc] : bias2[gc - 2048];
        }
#pragma unroll
        for (int p = 0; p < 2; ++p) {
#pragma unroll
            for (int ii = 0; ii < 2; ++ii) {
                const int i = 2 * p + ii;
#pragma unroll
                for (int j = 0; j < 4; ++j)
#pragma unroll
                    for (int k = 0; k < 4; ++k) {
                        const float v = acc[i][j][k] + bvj[j];
                        const __bf16 o = (MODE == 0) ? (__bf16)(v * fsigmoid(v))
                                                     : (__bf16)v;
                        sm.ct[((wave >> 1) * 32 + ii * 16 + quad * 4 + k) * 136 +
                              (wcol + j * 16 + r)] = o;
                    }
            }
            __syncthreads();
#pragma unroll
            for (int q = 0; q < 4; ++q) {
                const int chunk = q * 256 + tid;
                const int trow = chunk >> 4;
                const int tc = (chunk & 15) * 8;
                const bf16x8 vv = *(const bf16x8*)(sm.ct + trow * 136 + tc);
                const int grow = om0 + (trow >> 5) * 64 + p * 32 + (trow & 31);
                *(bf16x8*)(dst + (size_t)grow * stride + cb + tc) = vv;
            }
            __syncthreads();
        }
    }
}

// Parallel minGRU scan over one chunk, on raw pre-activations:
// z = sigmoid(raw_z), b = z * raw_h, h = (1-z)h + b.
// raw is [B*CS][4096] (z cols 0..2047, h cols 2048..4095).
// 256 blocks (full chip), 32-col groups x 32 segments x 1024 threads.
// (a,b) per timestep cached in registers; XCD-paired block remap.
#define SSEG 32
#define SCOLS 32
__global__ __launch_bounds__(1024)
void scan_kernel(const __bf16* __restrict__ raw, __bf16* __restrict__ xskip,
                 float* __restrict__ carry, int CS, int S, int t0, int first)
{
    __shared__ float Als[SSEG][SCOLS];
    __shared__ float Bls[SSEG][SCOLS];
    const int lane = threadIdx.x & (SCOLS - 1);   // col within group
    const int w = threadIdx.x >> 5;               // segment 0..31
    const int nb8 = gridDim.x >> 3;
    const int lin = (blockIdx.x & 7) * nb8 + (blockIdx.x >> 3);
    const int gpb = 2048 / SCOLS;                 // 64 groups per batch
    const int batch = lin / gpb;
    const int col = (lin - batch * gpb) * SCOLS + lane;
    const int L = CS / SSEG;                      // 32 (CS always 1024)
    const int tbeg = w * L;

    const size_t rbase = ((size_t)batch * CS + tbeg) * 4096 + col;

    float av[32], bv[32];
    float A = 1.0f, Bv = 0.0f;
    {
        size_t idx = rbase;
#pragma unroll
        for (int t = 0; t < 32; ++t, idx += 4096) {
            const float z = fsigmoid((float)raw[idx]);
            const float b = z * (float)raw[idx + 2048];
            const float a = 1.0f - z;
            av[t] = a;
            bv[t] = b;
            Bv = a * Bv + b;
            A *= a;
        }
    }
    Als[w][lane] = A;
    Bls[w][lane] = Bv;
    __syncthreads();

    const int ch = batch * 2048 + col;
    float h = first ? 0.0f : carry[ch];
    for (int s = 0; s < w; ++s)
        h = Als[s][lane] * h + Bls[s][lane];
    if (w == SSEG - 1)
        carry[ch] = A * h + Bv;

    {
        size_t gidx = ((size_t)batch * S + t0 + tbeg) * 2048 + col;
#pragma unroll
        for (int t = 0; t < 32; ++t, gidx += 2048) {
            h = av[t] * h + bv[t];
            xskip[gidx] = (__bf16)((float)xskip[gidx] + h);
        }
    }
}

__global__ __launch_bounds__(256)
void conv_f32_bf16(const float* __restrict__ x, __bf16* __restrict__ y, int n4)
{
    const int i = blockIdx.x * 256 + threadIdx.x;
    if (i >= n4) return;
    const float4 v = ((const float4*)x)[i];
    bf16x4 o;
    o[0] = (__bf16)v.x; o[1] = (__bf16)v.y; o[2] = (__bf16)v.z; o[3] = (__bf16)v.w;
    ((bf16x4*)y)[i] = o;
}

// W[K][N] fp32 -> Wt[N][K] bf16
__global__ __launch_bounds__(256)
void transpose_bf16(const float* __restrict__ W, __bf16* __restrict__ Wt, int K, int N)
{
    __shared__ float tile[32][33];
    const int tx = threadIdx.x & 31;
    const int ty = threadIdx.x >> 5;
    const int nb = blockIdx.x * 32;
    const int kb = blockIdx.y * 32;
#pragma unroll
    for (int i = 0; i < 32; i += 8)
        tile[ty + i][tx] = W[(size_t)(kb + ty + i) * N + nb + tx];
    __syncthreads();
#pragma unroll
    for (int i = 0; i < 32; i += 8)
        Wt[(size_t)(nb + ty + i) * K + kb + tx] = (__bf16)tile[tx][ty + i];
}

extern "C" void kernel_launch(void* const* d_in, const int* in_sizes, int n_in,
                              void* d_out, int out_size, void* d_ws, size_t ws_size,
                              hipStream_t stream)
{
    const float* x     = (const float*)d_in[0];
    const float* W_in1 = (const float*)d_in[1];
    const float* b_in1 = (const float*)d_in[2];
    const float* W_in2 = (const float*)d_in[3];
    const float* b_in2 = (const float*)d_in[4];
    const float* W_z   = (const float*)d_in[5];
    const float* b_z   = (const float*)d_in[6];
    const float* W_h   = (const float*)d_in[7];
    const float* b_h   = (const float*)d_in[8];
    const float* W_out = (const float*)d_in[9];
    const float* b_out = (const float*)d_in[10];

    const int B = 4, S = 4096, H = 512, E = 2048;
    const int M = B * S;        // 16384
    const int CS = 1024;        // chunk length
    const int NC = S / CS;      // 4 chunks
    const int MC = B * CS;      // 4096 rows per chunk

    const size_t MiB = 1024 * 1024;
    const size_t NEEDED = 183 * MiB;
    if (ws_size < NEEDED) return;

    char* ws = (char*)d_ws;
    __bf16* xb    = (__bf16*)(ws + 0);        // overlaid by rawzh after use
    __bf16* rawzh = (__bf16*)(ws + 0);
    float*  carry = (float*) (ws + 32 * MiB);
    __bf16* xin   = (__bf16*)(ws + 33 * MiB);
    __bf16* xskip = (__bf16*)(ws + 97 * MiB);
    __bf16* Wt12  = (__bf16*)(ws + 161 * MiB);
    __bf16* Wtzh  = (__bf16*)(ws + 165 * MiB);
    __bf16* Wto   = (__bf16*)(ws + 181 * MiB);

    conv_f32_bf16<<<(M * H / 4 + 255) / 256, 256, 0, stream>>>(x, xb, M * H / 4);
    transpose_bf16<<<dim3(E / 32, H / 32), 256, 0, stream>>>(W_in1, Wt12, H, E);
    transpose_bf16<<<dim3(E / 32, H / 32), 256, 0, stream>>>(W_in2, Wt12 + (size_t)E * H, H, E);
    transpose_bf16<<<dim3(E / 32, E / 32), 256, 0, stream>>>(W_z, Wtzh, E, E);
    transpose_bf16<<<dim3(E / 32, E / 32), 256, 0, stream>>>(W_h, Wtzh + (size_t)E * E, E, E);
    transpose_bf16<<<dim3(H / 32, E / 32), 256, 0, stream>>>(W_out, Wto, E, H);

    // Merged input GEMM: N=4096 (W1|W2), split-silu epilogue -> xin / xskip
    // 128^2 tiles (K=512 can't feed the 256^2 pipeline) + XCD swizzle.
    gemm_bt<0><<<dim3(M / 128, 2 * E / 128), 256, 0, stream>>>(
        xb, Wt12, b_in1, b_in2, xin, xskip, 2 * E, H, M / 128, 0, 0);

    // Recurrent stage, chunked over S (rawzh overlays dead xb)
    // 256^2 tiles: grid 16 x 16 = 256 blocks (1/CU), K=2048 (T=64).
    for (int c = 0; c < NC; ++c) {
        const int row_off = c * CS;
        gemm3<4><<<dim3(MC / 256, 2 * E / 256), 512, 0, stream>>>(
            xin, Wtzh, b_z, b_h, rawzh, nullptr, 2 * E, E, CS / 256, S, row_off);
        scan_kernel<<<(B * E) / SCOLS, 1024, 0, stream>>>(
            rawzh, xskip, carry, CS, S, row_off, c == 0);
    }

    // Output GEMM (full M), fp32 out -- 128^2 kernel (N=512).
    gemm_bt<3><<<dim3(M / 128, H / 128), 256, 0, stream>>>(
        xskip, Wto, b_out, nullptr, (float*)d_out, nullptr, H, E, M / 128, 0, 0);
}